// Round 2
// baseline (642.319 us; speedup 1.0000x reference)
//
#include <hip/hip_runtime.h>

// 2-layer LSTM (H=50) + FC head. Transposed-MFMA fp16, cross-layer pipelined.
// R15 = R14 + TWO BLOCKS PER CU: real batch tile halved to 8 (grid=512),
//   MFMA/LDS/role structure unchanged -- columns 8..15 compute duplicate
//   batches (staging loads batch b&7). Two unsynchronized blocks per CU
//   interleave their 513 barriers, filling the ~44% latency/barrier bubbles
//   R14 exposed (VALUBusy dropped 61->56 with NO time gain => latency-bound
//   at 16 waves/CU, not issue-bound). Budgets: 2x1024 thr = 2048 = CU max,
//   2x41.5 KB LDS = 83 <= 160 KB, VGPR 32.
// R14: shared-reciprocal cell (7 trans/cell, was 10) + split L2 MFMA chain.
// Wave roles (R12): 0..9 dual (L1 tile w + L2 tile w, prio 1), 10..12 L1
// single (12 feeds x), 13..15 L2 single (tiles 10..12).
// Core: gates^T = W @ h^T; A = weights in regs, B = h in LDS frag layout;
// gate rows permuted p=4j+g -> one lane owns a unit's 4 gates -> cell fully
// in-register; x + biases ride dead K-lanes (h1 k=50: x, k=51: 1.0);
// phase p = L1[p] + L2[p-1], ONE barrier/phase (513 = minimum).
// Lessons: max waves > fat waves (R10); no VGPR-squeezing launch_bounds (R3).

#define HID 50
#define SEQ 512
#define NB 16             // MFMA column count / LDS layout width (unchanged)
#define NBATCH 8          // REAL batches per block (R15)
#define NTHREADS 1024
#define XP 516            // xs row stride (floats)

typedef _Float16 f16x8 __attribute__((ext_vector_type(8)));
typedef float    f32x4 __attribute__((ext_vector_type(4)));

#define LOG2E 1.44269504f

// g[0]=-xi*log2e, g[1]=-xf*log2e, g[2]=+2xg*log2e, g[3]=-xo*log2e
// (scales folded into the weights at fragment-load time).
// sigmoid(xi) = 1/(1+e_i), tanh(xg) = (e_g-1)/(1+e_g) with e = exp2(g).
__device__ __forceinline__ float lstm_cell(const f32x4 g, float& c) {
    const float ei = __builtin_amdgcn_exp2f(g[0]);
    const float ef = __builtin_amdgcn_exp2f(g[1]);
    const float eg = __builtin_amdgcn_exp2f(g[2]);
    const float eo = __builtin_amdgcn_exp2f(g[3]);
    const float A  = ei + 1.0f;
    const float F  = ef + 1.0f;
    const float G  = eg + 1.0f;
    const float AG  = A * G;
    const float den = AG * F;                       // F*A*G  (<= ~2^54, safe)
    const float num = __builtin_fmaf(eg - 1.0f, F, c * AG);
    c = num * __builtin_amdgcn_rcpf(den);           // c' = f*c + i*tanh(xg)
    float z = c * (2.0f * LOG2E);
    z = __builtin_fminf(z, 100.0f);                 // tanh==1 beyond; no inf
    const float ec = __builtin_amdgcn_exp2f(z);
    return (ec - 1.0f) *
           __builtin_amdgcn_rcpf((eo + 1.0f) * (ec + 1.0f));  // o*tanh(c')
}

// h LDS layout: 16B chunk (kt*4+qh)*16 + m holds h[m][k = kt*32+qh*8+0..7].
// Reader (lane m=l15, quad qq, k-chunk kt) reads chunk (kt*4+qq)*16+m.
// Writer of h[m][j]: chunk ((j>>5)*4+((j>>3)&3))*16 + m, half j&7.
// j=50 -> chunk 96+m half 2 (x rides here), j=51 -> chunk 96+m half 3 (1.0).

__global__ __launch_bounds__(NTHREADS)
void lstm2_fc_v15(const float* __restrict__ x,
                  const float* __restrict__ w_ih0,
                  const float* __restrict__ w_hh0,
                  const float* __restrict__ b_ih0,
                  const float* __restrict__ b_hh0,
                  const float* __restrict__ w_ih1,
                  const float* __restrict__ w_hh1,
                  const float* __restrict__ b_ih1,
                  const float* __restrict__ b_hh1,
                  const float* __restrict__ fc_w,
                  const float* __restrict__ fc_b,
                  float* __restrict__ out)
{
    __shared__ float xs[NB * XP];        // 33 KB  x (rows 8..15 duplicate 0..7)
    __shared__ f16x8 h1f[2][128];        //  4 KB  h1 double-buffered, frag layout
    __shared__ f16x8 h2f[2][128];        //  4 KB  h2 double-buffered

    const int tid = threadIdx.x;
    const int b0  = blockIdx.x * NBATCH;         // 8 real batches per block
    const int w   = tid >> 6;            // wave id 0..15
    const int l15 = tid & 15;            // MFMA lane column (batch m)
    const int qq  = (tid >> 4) & 3;      // MFMA lane quad

    // ---- role assignment (wave-uniform) ----
    const bool dual  = (w <= 9);
    const bool hasL1 = (w <= 12);
    const bool hasL2 = dual || (w >= 13);
    const int  tL1   = w;                        // L1 tile (if hasL1)
    const int  tL2   = dual ? w : (w - 3);       // L2 tile (if hasL2)

    if (dual) __builtin_amdgcn_s_setprio(1);     // pacers issue first post-barrier

    // ---- stage x into LDS (coalesced float4); rows 8..15 duplicate 0..7 ----
    for (int idx = tid; idx < NB * 128; idx += NTHREADS) {
        const int b  = idx >> 7;
        const int t4 = idx & 127;
        *(float4*)&xs[b * XP + t4 * 4] =
            *(const float4*)&x[(size_t)(b0 + (b & 7)) * SEQ + t4 * 4];
    }
    if (tid < NB) {                       // zero x pad column t=512..515
        const float4 z = {0.f, 0.f, 0.f, 0.f};
        *(float4*)&xs[tid * XP + 512] = z;
    }
    // ---- zero h buffers ----
    if (tid < 256) {
        f16x8 z = {};
        h1f[tid >> 7][tid & 127] = z;
        h2f[tid >> 7][tid & 127] = z;
    }

    // ---- load weight A-fragments (one-time), gate rows permuted + SCALED ----
    // lane holds W[p = T*16 + l15][k = kt*32 + qq*8 + j], n(p)=(p&3)*HID+(p>>2)
    // row scale: gate (p&3)==2 (tanh) -> +2log2e, else (sigmoid) -> -log2e.
    // L1 frag (w_hh0): specials k=50 -> w_ih0, k=51 -> biasL1 (both scaled).
    // L2 frags: w_ih1 (special k=51 -> biasL2, scaled) and w_hh1.
    f16x8 wH0[2], wI1[2], wH1[2];
    {
        const int  p1  = tL1 * 16 + l15;
        const bool ok1 = hasL1 && (p1 < 4 * HID);
        const int  n1  = ok1 ? ((p1 & 3) * HID + (p1 >> 2)) : 0;
        const float s1 = ((p1 & 3) == 2) ? (2.0f * LOG2E) : -LOG2E;
        const int  p2  = tL2 * 16 + l15;
        const bool ok2 = hasL2 && (p2 < 4 * HID);
        const int  n2  = ok2 ? ((p2 & 3) * HID + (p2 >> 2)) : 0;
        const float s2 = ((p2 & 3) == 2) ? (2.0f * LOG2E) : -LOG2E;
#pragma unroll
        for (int kt = 0; kt < 2; ++kt) {
            f16x8 f0, f1, f2;
#pragma unroll
            for (int j = 0; j < 8; ++j) {
                const int k = kt * 32 + qq * 8 + j;
                float v0 = 0.0f, v1 = 0.0f, v2 = 0.0f;
                if (ok1) {
                    if (k < HID)          v0 = w_hh0[n1 * HID + k];
                    else if (k == HID)    v0 = w_ih0[n1];
                    else if (k == HID+1)  v0 = b_ih0[n1] + b_hh0[n1];
                    v0 *= s1;
                }
                if (ok2) {
                    if (k < HID)        { v1 = w_ih1[n2 * HID + k];
                                          v2 = w_hh1[n2 * HID + k]; }
                    else if (k == HID+1)  v1 = b_ih1[n2] + b_hh1[n2];
                    v1 *= s2;
                    v2 *= s2;
                }
                f0[j] = (_Float16)v0;
                f1[j] = (_Float16)v1;
                f2[j] = (_Float16)v2;
            }
            wH0[kt] = f0;
            wI1[kt] = f1;
            wH1[kt] = f2;
        }
    }

    // ---- per-lane invariants ----
    const int juL1   = tL1 * 4 + qq;             // unit of my L1 tile (<=51)
    const int juL2   = tL2 * 4 + qq;
    const int wOffL1 = ((((juL1 >> 5) * 4) + ((juL1 >> 3) & 3)) * 16 + l15) * 8 + (juL1 & 7);
    const int wOffL2 = ((((juL2 >> 5) * 4) + ((juL2 >> 3) & 3)) * 16 + l15) * 8 + (juL2 & 7);
    const int rdo = qq * 16 + l15;               // B-frag chunk index, kt=0
    const float* xrow = xs + l15 * XP;           // x row (wave 12, qq==2 feeds x)
    const f32x4 z4 = {0.f, 0.f, 0.f, 0.f};       // hoisted zero accumulator

    float c1 = 0.f, c2 = 0.f;

    __syncthreads();   // xs + zeros visible

    // ---- seed specials: h1f[0] k=50 = x[m][0]; k=51 = 1.0 in BOTH buffers.
    // The 1.0 lane (wave 12 qq=3) never writes in-loop, so both stay valid.
    if (tid < NB) {
        _Float16* e0 = (_Float16*)&h1f[0][96 + tid];
        e0[2] = (_Float16)xs[tid * XP];
        e0[3] = (_Float16)1.0f;
        ((_Float16*)&h1f[1][96 + tid])[3] = (_Float16)1.0f;
    }
    __syncthreads();

    // ---- phase body: L1-part [p], L2-part [p-1]; one barrier ----
    auto phase = [&](const f16x8* __restrict__ h1o, const f16x8* __restrict__ h2o,
                     f16x8* __restrict__ h1n, f16x8* __restrict__ h2n,
                     int p, bool doL1, bool doL2) {
        const f16x8 hb0 = h1o[rdo];              // shared by L1 and L2 parts
        const f16x8 hb1 = h1o[64 + rdo];
        if (hasL2 && doL2) {
            const f16x8 sb0 = h2o[rdo];
            const f16x8 sb1 = h2o[64 + rdo];
            // two independent 2-chains, merged with a vector add (v_pk_add)
            f32x4 acc_a, acc_b;
            acc_a = __builtin_amdgcn_mfma_f32_16x16x32_f16(wI1[0], hb0, z4,    0, 0, 0);
            acc_a = __builtin_amdgcn_mfma_f32_16x16x32_f16(wI1[1], hb1, acc_a, 0, 0, 0);
            acc_b = __builtin_amdgcn_mfma_f32_16x16x32_f16(wH1[0], sb0, z4,    0, 0, 0);
            acc_b = __builtin_amdgcn_mfma_f32_16x16x32_f16(wH1[1], sb1, acc_b, 0, 0, 0);
            const f32x4 acc = acc_a + acc_b;
            ((_Float16*)h2n)[wOffL2] = (_Float16)lstm_cell(acc, c2);
        }
        if (hasL1 && doL1) {
            f32x4 acc;
            acc = __builtin_amdgcn_mfma_f32_16x16x32_f16(wH0[0], hb0, z4,  0, 0, 0);
            acc = __builtin_amdgcn_mfma_f32_16x16x32_f16(wH0[1], hb1, acc, 0, 0, 0);
            const _Float16 hw = (_Float16)lstm_cell(acc, c1);
            if (w < 12) {                          // wave-uniform
                ((_Float16*)h1n)[wOffL1] = hw;
            } else {                               // wave 12: units 48..51
                if (qq < 2)       ((_Float16*)h1n)[wOffL1] = hw;
                else if (qq == 2) ((_Float16*)h1n)[wOffL1] =
                                      (_Float16)xrow[p + 1];
                /* qq == 3: the 1.0 lane, pre-seeded, never written */
            }
        }
        __syncthreads();
    };

    // phase p reads buf[p&1], writes buf[1-(p&1)]
    phase(h1f[0], h2f[0], h1f[1], h2f[1], 0, true, false);      // L1[0]
#pragma unroll 1
    for (int p = 1; p <= 509; p += 2) {
        phase(h1f[1], h2f[1], h1f[0], h2f[0], p,     true, true);
        phase(h1f[0], h2f[0], h1f[1], h2f[1], p + 1, true, true);
    }
    phase(h1f[1], h2f[1], h1f[0], h2f[0], 511, true,  true);
    phase(h1f[0], h2f[0], h1f[1], h2f[1], 512, false, true);    // L2[511]
    // h2[511] now lives in h2f[1]

    // ============ FC head: out[b] = h2[T-1] . fc_w + fc_b ============
    if (tid < NBATCH) {                   // only the 8 real batches
        const int m = tid;
        const _Float16* h2e = (const _Float16*)h2f[1];
        float s = fc_b[0];
        for (int j = 0; j < HID; ++j) {
            const int chunk = (((j >> 5) * 4) + ((j >> 3) & 3)) * 16 + m;
            s += fc_w[j] * (float)h2e[chunk * 8 + (j & 7)];
        }
        out[b0 + m] = s;
    }
}

extern "C" void kernel_launch(void* const* d_in, const int* in_sizes, int n_in,
                              void* d_out, int out_size, void* d_ws, size_t ws_size,
                              hipStream_t stream) {
    const float* x     = (const float*)d_in[0];
    const float* w_ih0 = (const float*)d_in[1];
    const float* w_hh0 = (const float*)d_in[2];
    const float* b_ih0 = (const float*)d_in[3];
    const float* b_hh0 = (const float*)d_in[4];
    const float* w_ih1 = (const float*)d_in[5];
    const float* w_hh1 = (const float*)d_in[6];
    const float* b_ih1 = (const float*)d_in[7];
    const float* b_hh1 = (const float*)d_in[8];
    const float* fc_w  = (const float*)d_in[9];
    const float* fc_b  = (const float*)d_in[10];
    float* out = (float*)d_out;

    const int B = in_sizes[0] / SEQ;  // 4096

    lstm2_fc_v15<<<B / NBATCH, NTHREADS, 0, stream>>>(
        x, w_ih0, w_hh0, b_ih0, b_hh0, w_ih1, w_hh1, b_ih1, b_hh1, fc_w, fc_b, out);
}

// Round 3
// 436.586 us; speedup vs baseline: 1.4712x; 1.4712x over previous
//
#include <hip/hip_runtime.h>

// 2-layer LSTM (H=50) + FC head. Transposed-MFMA fp16, cross-layer pipelined.
// R16 = R14 structure CONSOLIDATED ONTO 8 WAVES (512 threads):
//   B-fragments (hb/sb) depend only on the lane, not the tile -> a wave doing
//   k tile-tasks still needs only 4 ds_read_b128. 26 tile-tasks (13 L1 + 13
//   L2) over 8 waves: w0,w1: 2L1+2L2; w2..4: 2L1+1L2; w5..7: 1L1+2L2.
//   LDS read burst 58 -> 32 per phase (-45%), barrier participants 16 -> 8
//   (less convoy skew), 3-4 independent cell chains per wave (within-wave ILP
//   replaces cross-wave TLP). Total VALU/trans/MFMA issue per CU unchanged.
//   SIMD pairing (w%4): {w0,w4}=7 cells {w1,w5}=7 {w2,w6}=6 {w3,w7}=6.
// Lessons: R15: co-residency can't fill the bubbles (contended LDS/trans/
//   barrier, not empty issue slots) -- grid=256 x NB=16 real-work locked.
//   R14: cell chain depth matters when TLP is thin; count matters when ILP
//   is thick -> keep 7-trans cell here (4 chains/wave hide depth).
// Core: gates^T = W @ h^T; A = weights in regs, B = h in LDS frag layout;
// gate rows permuted p=4j+g -> one lane owns a unit's 4 gates -> cell fully
// in-register; x + biases ride dead K-lanes (h1 k=50: x, k=51: 1.0);
// phase p = L1[p] + L2[p-1], ONE barrier/phase (513 = minimum).

#define HID 50
#define SEQ 512
#define NB 16             // batches per block (MFMA column count)
#define NTHREADS 512      // 8 waves (R16)
#define XP 516            // xs row stride (floats)

typedef _Float16 f16x8 __attribute__((ext_vector_type(8)));
typedef float    f32x4 __attribute__((ext_vector_type(4)));

#define LOG2E 1.44269504f

// g[0]=-xi*log2e, g[1]=-xf*log2e, g[2]=+2xg*log2e, g[3]=-xo*log2e
// (scales folded into the weights at fragment-load time).
// sigmoid(xi) = 1/(1+e_i), tanh(xg) = (e_g-1)/(1+e_g) with e = exp2(g).
__device__ __forceinline__ float lstm_cell(const f32x4 g, float& c) {
    const float ei = __builtin_amdgcn_exp2f(g[0]);
    const float ef = __builtin_amdgcn_exp2f(g[1]);
    const float eg = __builtin_amdgcn_exp2f(g[2]);
    const float eo = __builtin_amdgcn_exp2f(g[3]);
    const float A  = ei + 1.0f;
    const float F  = ef + 1.0f;
    const float G  = eg + 1.0f;
    const float AG  = A * G;
    const float den = AG * F;                       // F*A*G  (<= ~2^54, safe)
    const float num = __builtin_fmaf(eg - 1.0f, F, c * AG);
    c = num * __builtin_amdgcn_rcpf(den);           // c' = f*c + i*tanh(xg)
    float z = c * (2.0f * LOG2E);
    z = __builtin_fminf(z, 100.0f);                 // tanh==1 beyond; no inf
    const float ec = __builtin_amdgcn_exp2f(z);
    return (ec - 1.0f) *
           __builtin_amdgcn_rcpf((eo + 1.0f) * (ec + 1.0f));  // o*tanh(c')
}

// h LDS layout: 16B chunk (kt*4+qh)*16 + m holds h[m][k = kt*32+qh*8+0..7].
// Reader (lane m=l15, quad qq, k-chunk kt) reads chunk (kt*4+qq)*16+m.
// Writer of h[m][j]: chunk ((j>>5)*4+((j>>3)&3))*16 + m, half j&7.
// j=50 -> chunk 96+m half 2 (x rides here), j=51 -> chunk 96+m half 3 (1.0).

__global__ __launch_bounds__(NTHREADS)
void lstm2_fc_v16(const float* __restrict__ x,
                  const float* __restrict__ w_ih0,
                  const float* __restrict__ w_hh0,
                  const float* __restrict__ b_ih0,
                  const float* __restrict__ b_hh0,
                  const float* __restrict__ w_ih1,
                  const float* __restrict__ w_hh1,
                  const float* __restrict__ b_ih1,
                  const float* __restrict__ b_hh1,
                  const float* __restrict__ fc_w,
                  const float* __restrict__ fc_b,
                  float* __restrict__ out)
{
    __shared__ float xs[NB * XP];        // 33 KB  x for all 512 steps
    __shared__ f16x8 h1f[2][128];        //  4 KB  h1 double-buffered, frag layout
    __shared__ f16x8 h2f[2][128];        //  4 KB  h2 double-buffered

    const int tid = threadIdx.x;
    const int b0  = blockIdx.x * NB;
    const int w   = tid >> 6;            // wave id 0..7
    const int l15 = tid & 15;            // MFMA lane column (batch m)
    const int qq  = (tid >> 4) & 3;      // MFMA lane quad

    // ---- task tables (wave-uniform) ----
    // L1 tiles: w0:{0,1} w1:{2,3} w2:{4,5} w3:{6,7} w4:{8,9} w5:{10} w6:{11} w7:{12}
    // L2 tiles: w0:{0,1} w1:{2,3} w2:{4}   w3:{5}   w4:{6}   w5:{7,8} w6:{9,10} w7:{11,12}
    const int nL1 = (w <= 4) ? 2 : 1;
    const int nL2 = (w <= 1 || w >= 5) ? 2 : 1;
    int tL1[2], tL2[2];
    tL1[0] = (w <= 4) ? 2 * w     : (w + 5);
    tL1[1] = (w <= 4) ? 2 * w + 1 : -1;
    tL2[0] = (w <= 1) ? 2 * w     : ((w <= 4) ? (w + 2) : (2 * w - 3));
    tL2[1] = (w <= 1) ? 2 * w + 1 : ((w >= 5) ? (2 * w - 2) : -1);

    if (w <= 1) __builtin_amdgcn_s_setprio(1);   // heaviest waves issue first

    // ---- stage x into LDS (coalesced float4) ----
    for (int idx = tid; idx < NB * 128; idx += NTHREADS) {
        const int b  = idx >> 7;
        const int t4 = idx & 127;
        *(float4*)&xs[b * XP + t4 * 4] =
            *(const float4*)&x[(size_t)(b0 + b) * SEQ + t4 * 4];
    }
    if (tid < NB) {                       // zero x pad column t=512..515
        const float4 z = {0.f, 0.f, 0.f, 0.f};
        *(float4*)&xs[tid * XP + 512] = z;
    }
    // ---- zero h buffers ----
    if (tid < 256) {
        f16x8 z = {};
        h1f[tid >> 7][tid & 127] = z;
        h2f[tid >> 7][tid & 127] = z;
    }

    // ---- load weight A-fragments (one-time), gate rows permuted + SCALED ----
    // lane holds W[p = T*16 + l15][k = kt*32 + qq*8 + j], n(p)=(p&3)*HID+(p>>2)
    // row scale: gate (p&3)==2 (tanh) -> +2log2e, else (sigmoid) -> -log2e.
    // L1 frag (w_hh0): specials k=50 -> w_ih0, k=51 -> biasL1 (both scaled).
    // L2 frags: w_ih1 (special k=51 -> biasL2, scaled) and w_hh1.
    f16x8 wH0[2][2], wI1[2][2], wH1[2][2];
#pragma unroll
    for (int s = 0; s < 2; ++s) {
        const int  p1  = tL1[s] * 16 + l15;
        const bool ok1 = (s < nL1) && (tL1[s] >= 0) && (p1 < 4 * HID);
        const int  n1  = ok1 ? ((p1 & 3) * HID + (p1 >> 2)) : 0;
        const float s1 = ((p1 & 3) == 2) ? (2.0f * LOG2E) : -LOG2E;
        const int  p2  = tL2[s] * 16 + l15;
        const bool ok2 = (s < nL2) && (tL2[s] >= 0) && (p2 < 4 * HID);
        const int  n2  = ok2 ? ((p2 & 3) * HID + (p2 >> 2)) : 0;
        const float s2 = ((p2 & 3) == 2) ? (2.0f * LOG2E) : -LOG2E;
#pragma unroll
        for (int kt = 0; kt < 2; ++kt) {
            f16x8 f0, f1, f2;
#pragma unroll
            for (int j = 0; j < 8; ++j) {
                const int k = kt * 32 + qq * 8 + j;
                float v0 = 0.0f, v1 = 0.0f, v2 = 0.0f;
                if (ok1) {
                    if (k < HID)          v0 = w_hh0[n1 * HID + k];
                    else if (k == HID)    v0 = w_ih0[n1];
                    else if (k == HID+1)  v0 = b_ih0[n1] + b_hh0[n1];
                    v0 *= s1;
                }
                if (ok2) {
                    if (k < HID)        { v1 = w_ih1[n2 * HID + k];
                                          v2 = w_hh1[n2 * HID + k]; }
                    else if (k == HID+1)  v1 = b_ih1[n2] + b_hh1[n2];
                    v1 *= s2;
                    v2 *= s2;
                }
                f0[j] = (_Float16)v0;
                f1[j] = (_Float16)v1;
                f2[j] = (_Float16)v2;
            }
            wH0[s][kt] = f0;
            wI1[s][kt] = f1;
            wH1[s][kt] = f2;
        }
    }

    // ---- per-lane invariants ----
    int  wOffL1[2], wOffL2[2];
    bool isXT[2];
#pragma unroll
    for (int s = 0; s < 2; ++s) {
        const int ju1 = tL1[s] * 4 + qq;
        wOffL1[s] = ((((ju1 >> 5) * 4) + ((ju1 >> 3) & 3)) * 16 + l15) * 8 + (ju1 & 7);
        const int ju2 = tL2[s] * 4 + qq;
        wOffL2[s] = ((((ju2 >> 5) * 4) + ((ju2 >> 3) & 3)) * 16 + l15) * 8 + (ju2 & 7);
        isXT[s] = (tL1[s] == 12);          // owns h1 units 48..51 (x + 1.0 lanes)
    }
    const int rdo = qq * 16 + l15;               // B-frag chunk index, kt=0
    const float* xrow = xs + l15 * XP;           // x row (x-feed wave, qq==2)
    const f32x4 z4 = {0.f, 0.f, 0.f, 0.f};       // hoisted zero accumulator

    float c1[2] = {0.f, 0.f}, c2[2] = {0.f, 0.f};

    __syncthreads();   // xs + zeros visible

    // ---- seed specials: h1f[0] k=50 = x[m][0]; k=51 = 1.0 in BOTH buffers.
    // The 1.0 lane (x-feed tile, qq=3) never writes in-loop, so both stay valid.
    if (tid < NB) {
        _Float16* e0 = (_Float16*)&h1f[0][96 + tid];
        e0[2] = (_Float16)xs[tid * XP];
        e0[3] = (_Float16)1.0f;
        ((_Float16*)&h1f[1][96 + tid])[3] = (_Float16)1.0f;
    }
    __syncthreads();

    // ---- phase body: L1-part [p], L2-part [p-1]; one barrier ----
    auto phase = [&](const f16x8* __restrict__ h1o, const f16x8* __restrict__ h2o,
                     f16x8* __restrict__ h1n, f16x8* __restrict__ h2n,
                     int p, bool doL1, bool doL2) {
        const f16x8 hb0 = h1o[rdo];              // shared by ALL tasks of this wave
        const f16x8 hb1 = h1o[64 + rdo];
        if (doL2) {
            const f16x8 sb0 = h2o[rdo];          // shared by both L2 tasks
            const f16x8 sb1 = h2o[64 + rdo];
#pragma unroll
            for (int s = 0; s < 2; ++s) if (s < nL2) {
                f32x4 acc_a, acc_b;
                acc_a = __builtin_amdgcn_mfma_f32_16x16x32_f16(wI1[s][0], hb0, z4,    0, 0, 0);
                acc_a = __builtin_amdgcn_mfma_f32_16x16x32_f16(wI1[s][1], hb1, acc_a, 0, 0, 0);
                acc_b = __builtin_amdgcn_mfma_f32_16x16x32_f16(wH1[s][0], sb0, z4,    0, 0, 0);
                acc_b = __builtin_amdgcn_mfma_f32_16x16x32_f16(wH1[s][1], sb1, acc_b, 0, 0, 0);
                const f32x4 acc = acc_a + acc_b;
                ((_Float16*)h2n)[wOffL2[s]] = (_Float16)lstm_cell(acc, c2[s]);
            }
        }
        if (doL1) {
#pragma unroll
            for (int s = 0; s < 2; ++s) if (s < nL1) {
                f32x4 acc;
                acc = __builtin_amdgcn_mfma_f32_16x16x32_f16(wH0[s][0], hb0, z4,  0, 0, 0);
                acc = __builtin_amdgcn_mfma_f32_16x16x32_f16(wH0[s][1], hb1, acc, 0, 0, 0);
                const _Float16 hw = (_Float16)lstm_cell(acc, c1[s]);
                if (!isXT[s]) {                    // wave-uniform per slot
                    ((_Float16*)h1n)[wOffL1[s]] = hw;
                } else {                           // tile 12: units 48..51
                    if (qq < 2)       ((_Float16*)h1n)[wOffL1[s]] = hw;
                    else if (qq == 2) ((_Float16*)h1n)[wOffL1[s]] =
                                          (_Float16)xrow[p + 1];
                    /* qq == 3: the 1.0 lane, pre-seeded, never written */
                }
            }
        }
        __syncthreads();
    };

    // phase p reads buf[p&1], writes buf[1-(p&1)]
    phase(h1f[0], h2f[0], h1f[1], h2f[1], 0, true, false);      // L1[0]
#pragma unroll 1
    for (int p = 1; p <= 509; p += 2) {
        phase(h1f[1], h2f[1], h1f[0], h2f[0], p,     true, true);
        phase(h1f[0], h2f[0], h1f[1], h2f[1], p + 1, true, true);
    }
    phase(h1f[1], h2f[1], h1f[0], h2f[0], 511, true,  true);
    phase(h1f[0], h2f[0], h1f[1], h2f[1], 512, false, true);    // L2[511]
    // h2[511] now lives in h2f[1]

    // ============ FC head: out[b] = h2[T-1] . fc_w + fc_b ============
    if (tid < NB) {
        const int m = tid;
        const _Float16* h2e = (const _Float16*)h2f[1];
        float s = fc_b[0];
        for (int j = 0; j < HID; ++j) {
            const int chunk = (((j >> 5) * 4) + ((j >> 3) & 3)) * 16 + m;
            s += fc_w[j] * (float)h2e[chunk * 8 + (j & 7)];
        }
        out[b0 + m] = s;
    }
}

extern "C" void kernel_launch(void* const* d_in, const int* in_sizes, int n_in,
                              void* d_out, int out_size, void* d_ws, size_t ws_size,
                              hipStream_t stream) {
    const float* x     = (const float*)d_in[0];
    const float* w_ih0 = (const float*)d_in[1];
    const float* w_hh0 = (const float*)d_in[2];
    const float* b_ih0 = (const float*)d_in[3];
    const float* b_hh0 = (const float*)d_in[4];
    const float* w_ih1 = (const float*)d_in[5];
    const float* w_hh1 = (const float*)d_in[6];
    const float* b_ih1 = (const float*)d_in[7];
    const float* b_hh1 = (const float*)d_in[8];
    const float* fc_w  = (const float*)d_in[9];
    const float* fc_b  = (const float*)d_in[10];
    float* out = (float*)d_out;

    const int B = in_sizes[0] / SEQ;  // 4096

    lstm2_fc_v16<<<B / NB, NTHREADS, 0, stream>>>(
        x, w_ih0, w_hh0, b_ih0, b_hh0, w_ih1, w_hh1, b_ih1, b_hh1, fc_w, fc_b, out);
}

// Round 4
// 387.761 us; speedup vs baseline: 1.6565x; 1.1259x over previous
//
#include <hip/hip_runtime.h>

// 2-layer LSTM (H=50) + FC head. Transposed-MFMA fp16, cross-layer pipelined.
// R17 = R14 (16 waves) + MATRIX-SPECIALIZED WAVE ROLES:
//   reads/wave are set by which MATRICES it touches (L2 task: hb+sb = 4 reads;
//   L1 task: hb = 2), not by tile count. R13/R14's 10 dual waves touched both
//   -> 58 reads/phase. Same 26 tasks re-packed: 7 L2-only waves (w0..5: 2
//   tiles, w6: 1) + 9 L1-only waves (w7..10: 2 tiles, w11..15: 1) -> 46
//   reads/phase (-21% LDS burst). Max 2 cells/wave, per-SIMD cells {7,7,6,6},
//   trans+MFMA totals unchanged. ONLY the burst + per-wave mix change.
// Lessons: R15 (2 blocks/CU, 2x work: 657) + R16 (8 waves: 406) bracket the
//   shape: 16 waves / 1 block per CU locked; read-cut must not cut waves.
//   R14: 7-trans shared-reciprocal cell kept (trans is the 2nd contended pipe).
// Core: gates^T = W @ h^T; A = weights in regs, B = h in LDS frag layout;
// gate rows permuted p=4j+g -> one lane owns a unit's 4 gates -> cell fully
// in-register; x + biases ride dead K-lanes (h1 k=50: x, k=51: 1.0);
// phase p = L1[p] + L2[p-1], ONE barrier/phase (513 = minimum).

#define HID 50
#define SEQ 512
#define NB 16             // batches per block (MFMA column count)
#define NTHREADS 1024     // 16 waves
#define XP 516            // xs row stride (floats)

typedef _Float16 f16x8 __attribute__((ext_vector_type(8)));
typedef float    f32x4 __attribute__((ext_vector_type(4)));

#define LOG2E 1.44269504f

// g[0]=-xi*log2e, g[1]=-xf*log2e, g[2]=+2xg*log2e, g[3]=-xo*log2e
// (scales folded into the weights at fragment-load time).
// sigmoid(xi) = 1/(1+e_i), tanh(xg) = (e_g-1)/(1+e_g) with e = exp2(g).
__device__ __forceinline__ float lstm_cell(const f32x4 g, float& c) {
    const float ei = __builtin_amdgcn_exp2f(g[0]);
    const float ef = __builtin_amdgcn_exp2f(g[1]);
    const float eg = __builtin_amdgcn_exp2f(g[2]);
    const float eo = __builtin_amdgcn_exp2f(g[3]);
    const float A  = ei + 1.0f;
    const float F  = ef + 1.0f;
    const float G  = eg + 1.0f;
    const float AG  = A * G;
    const float den = AG * F;                       // F*A*G  (<= ~2^54, safe)
    const float num = __builtin_fmaf(eg - 1.0f, F, c * AG);
    c = num * __builtin_amdgcn_rcpf(den);           // c' = f*c + i*tanh(xg)
    float z = c * (2.0f * LOG2E);
    z = __builtin_fminf(z, 100.0f);                 // tanh==1 beyond; no inf
    const float ec = __builtin_amdgcn_exp2f(z);
    return (ec - 1.0f) *
           __builtin_amdgcn_rcpf((eo + 1.0f) * (ec + 1.0f));  // o*tanh(c')
}

// h LDS layout: 16B chunk (kt*4+qh)*16 + m holds h[m][k = kt*32+qh*8+0..7].
// Reader (lane m=l15, quad qq, k-chunk kt) reads chunk (kt*4+qq)*16+m.
// Writer of h[m][j]: chunk ((j>>5)*4+((j>>3)&3))*16 + m, half j&7.
// j=50 -> chunk 96+m half 2 (x rides here), j=51 -> chunk 96+m half 3 (1.0).

__global__ __launch_bounds__(NTHREADS)
void lstm2_fc_v17(const float* __restrict__ x,
                  const float* __restrict__ w_ih0,
                  const float* __restrict__ w_hh0,
                  const float* __restrict__ b_ih0,
                  const float* __restrict__ b_hh0,
                  const float* __restrict__ w_ih1,
                  const float* __restrict__ w_hh1,
                  const float* __restrict__ b_ih1,
                  const float* __restrict__ b_hh1,
                  const float* __restrict__ fc_w,
                  const float* __restrict__ fc_b,
                  float* __restrict__ out)
{
    __shared__ float xs[NB * XP];        // 33 KB  x for all 512 steps
    __shared__ f16x8 h1f[2][128];        //  4 KB  h1 double-buffered, frag layout
    __shared__ f16x8 h2f[2][128];        //  4 KB  h2 double-buffered

    const int tid = threadIdx.x;
    const int b0  = blockIdx.x * NB;
    const int w   = tid >> 6;            // wave id 0..15
    const int l15 = tid & 15;            // MFMA lane column (batch m)
    const int qq  = (tid >> 4) & 3;      // MFMA lane quad

    // ---- matrix-specialized task tables (wave-uniform) ----
    // L2 waves: w0:{0,1} w1:{2,3} w2:{4,5} w3:{6,7} w4:{8,9} w5:{10,11} w6:{12}
    // L1 waves: w7:{0,1} w8:{2,3} w9:{4,5} w10:{6,7} w11:{8} w12:{9}
    //           w13:{10} w14:{11} w15:{12}   (w15 owns the x-feed tile 12)
    const int nL2 = (w <= 5) ? 2 : ((w == 6) ? 1 : 0);
    const int nL1 = (w >= 7) ? ((w <= 10) ? 2 : 1) : 0;
    int tL1[2], tL2[2];
    tL1[0] = (w >= 7) ? ((w <= 10) ? 2 * (w - 7) : (w - 3)) : -1;
    tL1[1] = (w >= 7 && w <= 10) ? 2 * (w - 7) + 1 : -1;
    tL2[0] = (w <= 5) ? 2 * w : ((w == 6) ? 12 : -1);
    tL2[1] = (w <= 5) ? 2 * w + 1 : -1;

    if (nL1 + nL2 >= 2) __builtin_amdgcn_s_setprio(1);  // heavy waves first

    // ---- stage x into LDS (coalesced float4) ----
    for (int idx = tid; idx < NB * 128; idx += NTHREADS) {
        const int b  = idx >> 7;
        const int t4 = idx & 127;
        *(float4*)&xs[b * XP + t4 * 4] =
            *(const float4*)&x[(size_t)(b0 + b) * SEQ + t4 * 4];
    }
    if (tid < NB) {                       // zero x pad column t=512..515
        const float4 z = {0.f, 0.f, 0.f, 0.f};
        *(float4*)&xs[tid * XP + 512] = z;
    }
    // ---- zero h buffers ----
    if (tid < 256) {
        f16x8 z = {};
        h1f[tid >> 7][tid & 127] = z;
        h2f[tid >> 7][tid & 127] = z;
    }

    // ---- load weight A-fragments (one-time), gate rows permuted + SCALED ----
    // lane holds W[p = T*16 + l15][k = kt*32 + qq*8 + j], n(p)=(p&3)*HID+(p>>2)
    // row scale: gate (p&3)==2 (tanh) -> +2log2e, else (sigmoid) -> -log2e.
    // L1 frag (w_hh0): specials k=50 -> w_ih0, k=51 -> biasL1 (both scaled).
    // L2 frags: w_ih1 (special k=51 -> biasL2, scaled) and w_hh1.
    f16x8 wH0[2][2], wI1[2][2], wH1[2][2];
#pragma unroll
    for (int s = 0; s < 2; ++s) {
        const int  t1  = (tL1[s] >= 0) ? tL1[s] : 0;
        const int  p1  = t1 * 16 + l15;
        const bool ok1 = (s < nL1) && (p1 < 4 * HID);
        const int  n1  = ok1 ? ((p1 & 3) * HID + (p1 >> 2)) : 0;
        const float s1 = ((p1 & 3) == 2) ? (2.0f * LOG2E) : -LOG2E;
        const int  t2  = (tL2[s] >= 0) ? tL2[s] : 0;
        const int  p2  = t2 * 16 + l15;
        const bool ok2 = (s < nL2) && (p2 < 4 * HID);
        const int  n2  = ok2 ? ((p2 & 3) * HID + (p2 >> 2)) : 0;
        const float s2 = ((p2 & 3) == 2) ? (2.0f * LOG2E) : -LOG2E;
#pragma unroll
        for (int kt = 0; kt < 2; ++kt) {
            f16x8 f0, f1, f2;
#pragma unroll
            for (int j = 0; j < 8; ++j) {
                const int k = kt * 32 + qq * 8 + j;
                float v0 = 0.0f, v1 = 0.0f, v2 = 0.0f;
                if (ok1) {
                    if (k < HID)          v0 = w_hh0[n1 * HID + k];
                    else if (k == HID)    v0 = w_ih0[n1];
                    else if (k == HID+1)  v0 = b_ih0[n1] + b_hh0[n1];
                    v0 *= s1;
                }
                if (ok2) {
                    if (k < HID)        { v1 = w_ih1[n2 * HID + k];
                                          v2 = w_hh1[n2 * HID + k]; }
                    else if (k == HID+1)  v1 = b_ih1[n2] + b_hh1[n2];
                    v1 *= s2;
                    v2 *= s2;
                }
                f0[j] = (_Float16)v0;
                f1[j] = (_Float16)v1;
                f2[j] = (_Float16)v2;
            }
            wH0[s][kt] = f0;
            wI1[s][kt] = f1;
            wH1[s][kt] = f2;
        }
    }

    // ---- per-lane invariants ----
    int  wOffL1[2], wOffL2[2];
    bool isXT[2];
#pragma unroll
    for (int s = 0; s < 2; ++s) {
        const int ju1 = ((tL1[s] >= 0) ? tL1[s] : 0) * 4 + qq;
        wOffL1[s] = ((((ju1 >> 5) * 4) + ((ju1 >> 3) & 3)) * 16 + l15) * 8 + (ju1 & 7);
        const int ju2 = ((tL2[s] >= 0) ? tL2[s] : 0) * 4 + qq;
        wOffL2[s] = ((((ju2 >> 5) * 4) + ((ju2 >> 3) & 3)) * 16 + l15) * 8 + (ju2 & 7);
        isXT[s] = (tL1[s] == 12);          // owns h1 units 48..51 (x + 1.0 lanes)
    }
    const int rdo = qq * 16 + l15;               // B-frag chunk index, kt=0
    const float* xrow = xs + l15 * XP;           // x row (x-feed wave, qq==2)
    const f32x4 z4 = {0.f, 0.f, 0.f, 0.f};       // hoisted zero accumulator

    float c1[2] = {0.f, 0.f}, c2[2] = {0.f, 0.f};

    __syncthreads();   // xs + zeros visible

    // ---- seed specials: h1f[0] k=50 = x[m][0]; k=51 = 1.0 in BOTH buffers.
    // The 1.0 lane (x-feed tile, qq=3) never writes in-loop, so both stay valid.
    if (tid < NB) {
        _Float16* e0 = (_Float16*)&h1f[0][96 + tid];
        e0[2] = (_Float16)xs[tid * XP];
        e0[3] = (_Float16)1.0f;
        ((_Float16*)&h1f[1][96 + tid])[3] = (_Float16)1.0f;
    }
    __syncthreads();

    // ---- phase body: L1-part [p], L2-part [p-1]; one barrier ----
    auto phase = [&](const f16x8* __restrict__ h1o, const f16x8* __restrict__ h2o,
                     f16x8* __restrict__ h1n, f16x8* __restrict__ h2n,
                     int p, bool doL1, bool doL2) {
        const f16x8 hb0 = h1o[rdo];              // all waves need h1
        const f16x8 hb1 = h1o[64 + rdo];
        if (nL2 > 0 && doL2) {
            const f16x8 sb0 = h2o[rdo];          // only L2 waves read h2
            const f16x8 sb1 = h2o[64 + rdo];
#pragma unroll
            for (int s = 0; s < 2; ++s) if (s < nL2) {
                f32x4 acc_a, acc_b;
                acc_a = __builtin_amdgcn_mfma_f32_16x16x32_f16(wI1[s][0], hb0, z4,    0, 0, 0);
                acc_a = __builtin_amdgcn_mfma_f32_16x16x32_f16(wI1[s][1], hb1, acc_a, 0, 0, 0);
                acc_b = __builtin_amdgcn_mfma_f32_16x16x32_f16(wH1[s][0], sb0, z4,    0, 0, 0);
                acc_b = __builtin_amdgcn_mfma_f32_16x16x32_f16(wH1[s][1], sb1, acc_b, 0, 0, 0);
                const f32x4 acc = acc_a + acc_b;
                ((_Float16*)h2n)[wOffL2[s]] = (_Float16)lstm_cell(acc, c2[s]);
            }
        }
        if (nL1 > 0 && doL1) {
#pragma unroll
            for (int s = 0; s < 2; ++s) if (s < nL1) {
                f32x4 acc;
                acc = __builtin_amdgcn_mfma_f32_16x16x32_f16(wH0[s][0], hb0, z4,  0, 0, 0);
                acc = __builtin_amdgcn_mfma_f32_16x16x32_f16(wH0[s][1], hb1, acc, 0, 0, 0);
                const _Float16 hw = (_Float16)lstm_cell(acc, c1[s]);
                if (!isXT[s]) {                    // wave-uniform per slot
                    ((_Float16*)h1n)[wOffL1[s]] = hw;
                } else {                           // tile 12: units 48..51
                    if (qq < 2)       ((_Float16*)h1n)[wOffL1[s]] = hw;
                    else if (qq == 2) ((_Float16*)h1n)[wOffL1[s]] =
                                          (_Float16)xrow[p + 1];
                    /* qq == 3: the 1.0 lane, pre-seeded, never written */
                }
            }
        }
        __syncthreads();
    };

    // phase p reads buf[p&1], writes buf[1-(p&1)]
    phase(h1f[0], h2f[0], h1f[1], h2f[1], 0, true, false);      // L1[0]
#pragma unroll 1
    for (int p = 1; p <= 509; p += 2) {
        phase(h1f[1], h2f[1], h1f[0], h2f[0], p,     true, true);
        phase(h1f[0], h2f[0], h1f[1], h2f[1], p + 1, true, true);
    }
    phase(h1f[1], h2f[1], h1f[0], h2f[0], 511, true,  true);
    phase(h1f[0], h2f[0], h1f[1], h2f[1], 512, false, true);    // L2[511]
    // h2[511] now lives in h2f[1]

    // ============ FC head: out[b] = h2[T-1] . fc_w + fc_b ============
    if (tid < NB) {
        const int m = tid;
        const _Float16* h2e = (const _Float16*)h2f[1];
        float s = fc_b[0];
        for (int j = 0; j < HID; ++j) {
            const int chunk = (((j >> 5) * 4) + ((j >> 3) & 3)) * 16 + m;
            s += fc_w[j] * (float)h2e[chunk * 8 + (j & 7)];
        }
        out[b0 + m] = s;
    }
}

extern "C" void kernel_launch(void* const* d_in, const int* in_sizes, int n_in,
                              void* d_out, int out_size, void* d_ws, size_t ws_size,
                              hipStream_t stream) {
    const float* x     = (const float*)d_in[0];
    const float* w_ih0 = (const float*)d_in[1];
    const float* w_hh0 = (const float*)d_in[2];
    const float* b_ih0 = (const float*)d_in[3];
    const float* b_hh0 = (const float*)d_in[4];
    const float* w_ih1 = (const float*)d_in[5];
    const float* w_hh1 = (const float*)d_in[6];
    const float* b_ih1 = (const float*)d_in[7];
    const float* b_hh1 = (const float*)d_in[8];
    const float* fc_w  = (const float*)d_in[9];
    const float* fc_b  = (const float*)d_in[10];
    float* out = (float*)d_out;

    const int B = in_sizes[0] / SEQ;  // 4096

    lstm2_fc_v17<<<B / NB, NTHREADS, 0, stream>>>(
        x, w_ih0, w_hh0, b_ih0, b_hh0, w_ih1, w_hh1, b_ih1, b_hh1, fc_w, fc_b, out);
}